// Round 10
// baseline (235.673 us; speedup 1.0000x reference)
//
#include <hip/hip_runtime.h>
#include <hip/hip_bf16.h>
#include <math.h>

// RBF_Conv2d cdist via MFMA implicit GEMM (round 10).
// acc = sum_d A[o][d]*B[d][p] over padded K=80:
//   d<75 : A = bf16(-2*w), B = bf16_rne(x)
//   d=75 : A = wn_hi, B = 1.0   d=76 : A = wn_lo, B = 1.0
//   d=77 : A = 1.0,   B = pn_hi d=78 : A = 1.0,   B = pn_lo
// acc == d2 = pn + wn - 2*dot; epilogue = v_sqrt(max(acc,0)).
// CORRECTNESS RULE: MFMA operands are wave-collective -- builds may be
// lane-divergent, but every MFMA issues after re-convergence.
// Round-10: row-per-wave mapping (no per-strip div), 3-tier edge paths,
// v_sqrt_f32 epilogue, nontemporal stores, 64-thread blocks.

#define KH 5
#define KW 5
#define PAD 2
#define CH 3
#define DD 75
#define OC 64
#define HH 224
#define WW 224
#define HW (HH * WW)

using short8_t = __attribute__((ext_vector_type(8))) short;
using f32x16   = __attribute__((ext_vector_type(16))) float;

union Oct { unsigned int w[4]; short8_t v; };

__device__ inline unsigned int rne_bf16(float v) {
    return (unsigned int)__builtin_bit_cast(unsigned short, __float2bfloat16(v));
}

__device__ inline float fsqrt_fast(float x) {
    float r;
    asm("v_sqrt_f32 %0, %1" : "=v"(r) : "v"(x));   // ~1ulp, fine vs 0.254 thr
    return r;
}

// MODE: 0 = interior (no checks), 1 = x-clamp only, 2 = full clamp.
// d is a constant after unroll+inline -> c,i,j and offsets fold.
template<int MODE>
__device__ inline float xelem(const float* __restrict__ xb, int y, int xp, int d) {
    if (d >= DD) return 0.f;
    const int c = d / 25, rem = d % 25, i = rem / 5, j = rem % 5;
    int gy = y + i - PAD;
    int gx = xp + j;
    if constexpr (MODE == 0) {
        return xb[(c * HH + gy) * WW + gx];
    } else if constexpr (MODE == 1) {
        bool ok = (unsigned)gx < (unsigned)WW;
        int gxc = min(max(gx, 0), WW - 1);
        float v = xb[(c * HH + gy) * WW + gxc];
        return ok ? v : 0.f;
    } else {
        bool ok = ((unsigned)gy < (unsigned)HH) & ((unsigned)gx < (unsigned)WW);
        int gyc = min(max(gy, 0), HH - 1);
        int gxc = min(max(gx, 0), WW - 1);
        float v = xb[(c * HH + gyc) * WW + gxc];
        return ok ? v : 0.f;
    }
}

template<int D0, int MODE>
__device__ inline void build_oct_rne(const float* __restrict__ xb, int y, int xp,
                                     float& pn, Oct& b) {
#pragma unroll
    for (int rr = 0; rr < 8; rr += 2) {
        float v0 = xelem<MODE>(xb, y, xp, D0 + rr);
        float v1 = xelem<MODE>(xb, y, xp, D0 + rr + 1);
        pn = fmaf(v0, v0, pn);
        pn = fmaf(v1, v1, pn);
        b.w[rr >> 1] = rne_bf16(v0) | (rne_bf16(v1) << 16);
    }
}

template<int D0>
__device__ inline void build_aoct(const float* __restrict__ wrow, Oct& a) {
#pragma unroll
    for (int rr = 0; rr < 8; rr += 2) {
        float v0 = (D0 + rr     < DD) ? (-2.f * wrow[D0 + rr])     : 0.f;
        float v1 = (D0 + rr + 1 < DD) ? (-2.f * wrow[D0 + rr + 1]) : 0.f;
        a.w[rr >> 1] = rne_bf16(v0) | (rne_bf16(v1) << 16);
    }
}

#define MFMA(A, B, C) __builtin_amdgcn_mfma_f32_32x32x16_bf16((A), (B), (C), 0, 0, 0)

template<int MODE>
__device__ inline void do_strip(const float* __restrict__ xb, int y, int xp, int hi,
                                const Oct (&ah)[2][5], float* __restrict__ op) {
    float pnp = 0.f;
    Oct bh[5];
    // builds divergent on hi (compile-time D0 per half-wave)...
    if (hi == 0) {
        build_oct_rne<0,  MODE>(xb, y, xp, pnp, bh[0]);
        build_oct_rne<16, MODE>(xb, y, xp, pnp, bh[1]);
        build_oct_rne<32, MODE>(xb, y, xp, pnp, bh[2]);
        build_oct_rne<48, MODE>(xb, y, xp, pnp, bh[3]);
        build_oct_rne<64, MODE>(xb, y, xp, pnp, bh[4]);
    } else {
        build_oct_rne<8,  MODE>(xb, y, xp, pnp, bh[0]);
        build_oct_rne<24, MODE>(xb, y, xp, pnp, bh[1]);
        build_oct_rne<40, MODE>(xb, y, xp, pnp, bh[2]);
        build_oct_rne<56, MODE>(xb, y, xp, pnp, bh[3]);
        build_oct_rne<72, MODE>(xb, y, xp, pnp, bh[4]);   // d75..79 -> 0
    }
    float pn = pnp + __shfl_xor(pnp, 32);   // partner half-wave has other d's
    if (hi == 1) {
        // B pad slots (octet d72..79): elem3=1, elem4=1, elem5=pn_hi, elem6=pn_lo
        unsigned int up  = __builtin_bit_cast(unsigned int, pn);
        float pnhv = __builtin_bit_cast(float, up & 0xFFFF0000u);
        unsigned int pnl = rne_bf16(pn - pnhv);
        bh[4].w[1] |= 0x3F800000u;
        bh[4].w[2]  = 0x3F80u | (up & 0xFFFF0000u);
        bh[4].w[3]  = pnl;
    }

    // ...MFMAs only here, fully re-converged.
    f32x16 acc0 = {0.f,0.f,0.f,0.f,0.f,0.f,0.f,0.f,0.f,0.f,0.f,0.f,0.f,0.f,0.f,0.f};
    f32x16 acc1 = acc0;
#pragma unroll
    for (int st = 0; st < 5; ++st) {
        acc0 = MFMA(ah[0][st].v, bh[st].v, acc0);
        acc1 = MFMA(ah[1][st].v, bh[st].v, acc1);
    }

    // C/D: col = lane&31, row = (reg&3)+8*(reg>>2)+4*hi (+32 for acc1); +4*hi in op.
#pragma unroll
    for (int reg = 0; reg < 16; ++reg) {
        int ob = (reg & 3) + 8 * (reg >> 2);
        __builtin_nontemporal_store(fsqrt_fast(fmaxf(acc0[reg], 0.f)),
                                    op + (size_t)ob * HW);
        __builtin_nontemporal_store(fsqrt_fast(fmaxf(acc1[reg], 0.f)),
                                    op + (size_t)(ob + 32) * HW);
    }
}

__global__ __launch_bounds__(64, 4) void rbf_mfma(const float* __restrict__ x,
                                                  const float* __restrict__ w,
                                                  float* __restrict__ out) {
    const int lane = threadIdx.x;     // 64-thread block == one wave
    const int l31  = lane & 31;
    const int hi   = lane >> 5;

    // ---- one-time A-fragment + wn build (amortized over 14 strips) ----
    float wn[2];
#pragma unroll
    for (int mt = 0; mt < 2; ++mt) {
        const float* wrow = w + (l31 + 32 * mt) * DD;
        float s = 0.f;
#pragma unroll 5
        for (int d = 0; d < DD; ++d) { float v = wrow[d]; s = fmaf(v, v, s); }
        wn[mt] = s;
    }
    Oct ah[2][5];
    if (hi == 0) {
#pragma unroll
        for (int mt = 0; mt < 2; ++mt) {
            const float* wrow = w + (l31 + 32 * mt) * DD;
            build_aoct<0 >(wrow, ah[mt][0]);
            build_aoct<16>(wrow, ah[mt][1]);
            build_aoct<32>(wrow, ah[mt][2]);
            build_aoct<48>(wrow, ah[mt][3]);
            build_aoct<64>(wrow, ah[mt][4]);
        }
    } else {
#pragma unroll
        for (int mt = 0; mt < 2; ++mt) {
            const float* wrow = w + (l31 + 32 * mt) * DD;
            build_aoct<8 >(wrow, ah[mt][0]);
            build_aoct<24>(wrow, ah[mt][1]);
            build_aoct<40>(wrow, ah[mt][2]);
            build_aoct<56>(wrow, ah[mt][3]);
            build_aoct<72>(wrow, ah[mt][4]);
            // A pad slots: elem3=wn_hi, elem4=wn_lo, elem5=1.0, elem6=1.0, elem7=0
            unsigned int uwn = __builtin_bit_cast(unsigned int, wn[mt]);
            float wnhv = __builtin_bit_cast(float, uwn & 0xFFFF0000u);
            unsigned int wnl = rne_bf16(wn[mt] - wnhv);
            ah[mt][4].w[1] = (ah[mt][4].w[1] & 0xFFFFu) | (uwn & 0xFFFF0000u);
            ah[mt][4].w[2] = wnl | (0x3F80u << 16);
            ah[mt][4].w[3] = 0x3F80u;
        }
    }

    // ---- 2 rows per wave; 7 strips per row; k-position static ----
    const int r0 = blockIdx.x * 2;
#pragma unroll 1
    for (int rr = 0; rr < 2; ++rr) {
        int r = r0 + rr;
        int b = r / HH;
        int y = r - b * HH;
        const float* xb = x + (size_t)b * (CH * HW);
        float* oprow = out + (size_t)b * OC * HW + (size_t)y * WW
                           + (size_t)hi * 4 * HW + l31;
        bool yedge = (y < PAD) | (y >= HH - PAD);
        if (yedge) {
#pragma unroll 1
            for (int k = 0; k < 7; ++k)
                do_strip<2>(xb, y, k * 32 + l31 - PAD, hi, ah, oprow + k * 32);
        } else {
            do_strip<1>(xb, y, 0 * 32 + l31 - PAD, hi, ah, oprow + 0 * 32);
#pragma unroll 1
            for (int k = 1; k < 6; ++k)
                do_strip<0>(xb, y, k * 32 + l31 - PAD, hi, ah, oprow + k * 32);
            do_strip<1>(xb, y, 6 * 32 + l31 - PAD, hi, ah, oprow + 6 * 32);
        }
    }
}

extern "C" void kernel_launch(void* const* d_in, const int* in_sizes, int n_in,
                              void* d_out, int out_size, void* d_ws, size_t ws_size,
                              hipStream_t stream) {
    const float* x = (const float*)d_in[0];
    const float* w = (const float*)d_in[1];
    float* out     = (float*)d_out;

    int B       = in_sizes[0] / (CH * HW);   // 32
    int nrows   = B * HH;                    // 7168
    int nblocks = nrows / 2;                 // 3584 wave-blocks, 2 rows each

    rbf_mfma<<<nblocks, 64, 0, stream>>>(x, w, out);
}

// Round 11
// 139.153 us; speedup vs baseline: 1.6936x; 1.6936x over previous
//
#include <hip/hip_runtime.h>
#include <hip/hip_bf16.h>
#include <math.h>

// RBF_Conv2d cdist via MFMA implicit GEMM (round 11 = round 9 + LDS w-staging + fast sqrt).
// acc = sum_d A[o][d]*B[d][p] over padded K=80:
//   d<75 : A = bf16(-2*w), B = bf16_rne(x)
//   d=75 : A = wn_hi, B = 1.0   d=76 : A = wn_lo, B = 1.0
//   d=77 : A = 1.0,   B = pn_hi d=78 : A = 1.0,   B = pn_lo
// acc == d2 = pn + wn - 2*dot; epilogue = v_sqrt(max(acc,0)).
// CORRECTNESS RULE: MFMA operands are wave-collective -- builds may be
// lane-divergent, but every MFMA issues after re-convergence.
// Round-11 theory: round 9's dominant cost was per-wave A-setup reading w at
// stride-300B (~64 L1 lines per load inst, ~235K L1 lookups/CU). Stage w in
// LDS once per block (coalesced), build fragments from LDS. Keep regular
// (cached) stores -- round 10 showed nontemporal inflates WRITE_SIZE 22%.

#define KH 5
#define KW 5
#define PAD 2
#define CH 3
#define DD 75
#define OC 64
#define HH 224
#define WW 224
#define HW (HH * WW)
#define NSX 7            // 224/32 strips per row

using short8_t = __attribute__((ext_vector_type(8))) short;
using f32x16   = __attribute__((ext_vector_type(16))) float;

union Oct { unsigned int w[4]; short8_t v; };

__device__ inline unsigned int rne_bf16(float v) {
    return (unsigned int)__builtin_bit_cast(unsigned short, __float2bfloat16(v));
}

__device__ inline float fsqrt_fast(float x) {
    float r;
    asm("v_sqrt_f32 %0, %1" : "=v"(r) : "v"(x));   // ~1ulp; validated round 10
    return r;
}

// window element value; d is constant after unroll+inline -> all math folds.
template<bool EDGE>
__device__ inline float xelem(const float* __restrict__ xb, int y, int xp, int d) {
    if (d >= DD) return 0.f;
    const int c = d / 25, rem = d % 25, i = rem / 5, j = rem % 5;
    int gy = y + i - PAD;
    int gx = xp + j;
    if constexpr (!EDGE) {
        return xb[(c * HH + gy) * WW + gx];
    } else {
        bool ok = ((unsigned)gy < (unsigned)HH) & ((unsigned)gx < (unsigned)WW);
        int gyc = min(max(gy, 0), HH - 1);
        int gxc = min(max(gx, 0), WW - 1);
        float raw = xb[(c * HH + gyc) * WW + gxc];
        return ok ? raw : 0.f;
    }
}

template<int D0, bool EDGE>
__device__ inline void build_oct_rne(const float* __restrict__ xb, int y, int xp,
                                     float& pn, Oct& b) {
#pragma unroll
    for (int rr = 0; rr < 8; rr += 2) {
        float v0 = xelem<EDGE>(xb, y, xp, D0 + rr);
        float v1 = xelem<EDGE>(xb, y, xp, D0 + rr + 1);
        pn = fmaf(v0, v0, pn);
        pn = fmaf(v1, v1, pn);
        b.w[rr >> 1] = rne_bf16(v0) | (rne_bf16(v1) << 16);
    }
}

// A-octet build from LDS-resident w row; also accumulates this lane's
// partial ||w||^2 over the d's it owns (partner half-wave has the rest).
template<int D0>
__device__ inline void build_aoct_wn(const float* wrow, Oct& a, float& wns) {
#pragma unroll
    for (int rr = 0; rr < 8; rr += 2) {
        float r0 = (D0 + rr     < DD) ? wrow[D0 + rr]     : 0.f;
        float r1 = (D0 + rr + 1 < DD) ? wrow[D0 + rr + 1] : 0.f;
        wns = fmaf(r0, r0, wns);
        wns = fmaf(r1, r1, wns);
        a.w[rr >> 1] = rne_bf16(-2.f * r0) | (rne_bf16(-2.f * r1) << 16);
    }
}

#define MFMA(A, B, C) __builtin_amdgcn_mfma_f32_32x32x16_bf16((A), (B), (C), 0, 0, 0)

template<bool EDGE>
__device__ inline void do_strip(const float* __restrict__ xb, int y, int xp, int hi,
                                const Oct (&ah)[2][5], float* __restrict__ op) {
    float pnp = 0.f;
    Oct bh[5];
    // builds divergent on hi (compile-time D0 per half-wave)...
    if (hi == 0) {
        build_oct_rne<0,  EDGE>(xb, y, xp, pnp, bh[0]);
        build_oct_rne<16, EDGE>(xb, y, xp, pnp, bh[1]);
        build_oct_rne<32, EDGE>(xb, y, xp, pnp, bh[2]);
        build_oct_rne<48, EDGE>(xb, y, xp, pnp, bh[3]);
        build_oct_rne<64, EDGE>(xb, y, xp, pnp, bh[4]);
    } else {
        build_oct_rne<8,  EDGE>(xb, y, xp, pnp, bh[0]);
        build_oct_rne<24, EDGE>(xb, y, xp, pnp, bh[1]);
        build_oct_rne<40, EDGE>(xb, y, xp, pnp, bh[2]);
        build_oct_rne<56, EDGE>(xb, y, xp, pnp, bh[3]);
        build_oct_rne<72, EDGE>(xb, y, xp, pnp, bh[4]);   // d75..79 -> 0
    }
    float pn = pnp + __shfl_xor(pnp, 32);   // partner half-wave has other d's
    if (hi == 1) {
        // B pad slots (octet d72..79): elem3=1, elem4=1, elem5=pn_hi, elem6=pn_lo
        unsigned int up  = __builtin_bit_cast(unsigned int, pn);
        float pnhv = __builtin_bit_cast(float, up & 0xFFFF0000u);
        unsigned int pnl = rne_bf16(pn - pnhv);
        bh[4].w[1] |= 0x3F800000u;
        bh[4].w[2]  = 0x3F80u | (up & 0xFFFF0000u);
        bh[4].w[3]  = pnl;
    }

    // ...MFMAs only here, fully re-converged.
    f32x16 acc0 = {0.f,0.f,0.f,0.f,0.f,0.f,0.f,0.f,0.f,0.f,0.f,0.f,0.f,0.f,0.f,0.f};
    f32x16 acc1 = acc0;
#pragma unroll
    for (int st = 0; st < 5; ++st) {
        acc0 = MFMA(ah[0][st].v, bh[st].v, acc0);
        acc1 = MFMA(ah[1][st].v, bh[st].v, acc1);
    }

    // C/D: col = lane&31, row = (reg&3)+8*(reg>>2)+4*hi (+32 for acc1); +4*hi in op.
#pragma unroll
    for (int reg = 0; reg < 16; ++reg) {
        int ob = (reg & 3) + 8 * (reg >> 2);
        op[(size_t)ob * HW]        = fsqrt_fast(fmaxf(acc0[reg], 0.f));
        op[(size_t)(ob + 32) * HW] = fsqrt_fast(fmaxf(acc1[reg], 0.f));
    }
}

__global__ __launch_bounds__(256, 4) void rbf_mfma(const float* __restrict__ x,
                                                   const float* __restrict__ w,
                                                   float* __restrict__ out,
                                                   int nstrips, int nwaves) {
    __shared__ float wlds[OC * DD];          // 19.2 KB
    const int tid  = threadIdx.x;

    // ---- coalesced global->LDS staging of w (once per block) ----
    for (int idx = tid; idx < OC * DD; idx += 256)
        wlds[idx] = w[idx];
    __syncthreads();

    const int lane = tid & 63;
    const int l31  = lane & 31;
    const int hi   = lane >> 5;

    // ---- A-fragment + wn build from LDS (stride-75 across lanes: 2-way banks, free) ----
    float wnp[2] = {0.f, 0.f};
    Oct ah[2][5];
    if (hi == 0) {
#pragma unroll
        for (int mt = 0; mt < 2; ++mt) {
            const float* wrow = wlds + (l31 + 32 * mt) * DD;
            build_aoct_wn<0 >(wrow, ah[mt][0], wnp[mt]);
            build_aoct_wn<16>(wrow, ah[mt][1], wnp[mt]);
            build_aoct_wn<32>(wrow, ah[mt][2], wnp[mt]);
            build_aoct_wn<48>(wrow, ah[mt][3], wnp[mt]);
            build_aoct_wn<64>(wrow, ah[mt][4], wnp[mt]);
        }
    } else {
#pragma unroll
        for (int mt = 0; mt < 2; ++mt) {
            const float* wrow = wlds + (l31 + 32 * mt) * DD;
            build_aoct_wn<8 >(wrow, ah[mt][0], wnp[mt]);
            build_aoct_wn<24>(wrow, ah[mt][1], wnp[mt]);
            build_aoct_wn<40>(wrow, ah[mt][2], wnp[mt]);
            build_aoct_wn<56>(wrow, ah[mt][3], wnp[mt]);
            build_aoct_wn<72>(wrow, ah[mt][4], wnp[mt]);
        }
    }
    // full ||w||^2 per mt: partner half-wave (same row) holds the other d's
    float wn0 = wnp[0] + __shfl_xor(wnp[0], 32);
    float wn1 = wnp[1] + __shfl_xor(wnp[1], 32);
    if (hi == 1) {
#pragma unroll
        for (int mt = 0; mt < 2; ++mt) {
            // A pad slots: elem3=wn_hi, elem4=wn_lo, elem5=1.0, elem6=1.0, elem7=0
            float wnv = mt ? wn1 : wn0;
            unsigned int uwn = __builtin_bit_cast(unsigned int, wnv);
            float wnhv = __builtin_bit_cast(float, uwn & 0xFFFF0000u);
            unsigned int wnl = rne_bf16(wnv - wnhv);
            ah[mt][4].w[1] = (ah[mt][4].w[1] & 0xFFFFu) | (uwn & 0xFFFF0000u);
            ah[mt][4].w[2] = wnl | (0x3F80u << 16);
            ah[mt][4].w[3] = 0x3F80u;
        }
    }

    // ---- strip loop (identical to round 9) ----
    const int gw = blockIdx.x * 4 + (tid >> 6);
    for (int s = gw; s < nstrips; s += nwaves) {
        int sx = s % NSX;
        int t  = s / NSX;
        int y  = t % HH;
        int b  = t / HH;
        int x0 = sx * 32;
        const float* xb = x + (size_t)b * (CH * HW);
        int xp = x0 + l31 - PAD;
        float* op = out + (size_t)b * OC * HW + (size_t)(y * WW + x0 + l31)
                        + (size_t)hi * 4 * HW;
        bool interior = (y >= PAD) & (y < HH - PAD) & (sx >= 1) & (sx <= 5);
        if (interior) do_strip<false>(xb, y, xp, hi, ah, op);
        else          do_strip<true >(xb, y, xp, hi, ah, op);
    }
}

extern "C" void kernel_launch(void* const* d_in, const int* in_sizes, int n_in,
                              void* d_out, int out_size, void* d_ws, size_t ws_size,
                              hipStream_t stream) {
    const float* x = (const float*)d_in[0];
    const float* w = (const float*)d_in[1];
    float* out     = (float*)d_out;

    int B       = in_sizes[0] / (CH * HW);   // 32
    int nstrips = B * HH * NSX;              // 50176
    int nblocks = 1024;                      // 4 blocks/CU -> 4 waves/SIMD
    int nwaves  = nblocks * 4;

    rbf_mfma<<<nblocks, 256, 0, stream>>>(x, w, out, nstrips, nwaves);
}

// Round 12
// 112.666 us; speedup vs baseline: 2.0918x; 1.2351x over previous
//
#include <hip/hip_runtime.h>
#include <hip/hip_bf16.h>
#include <math.h>

// RBF_Conv2d cdist via MFMA implicit GEMM (round 12 = round 11 + locality mapping).
// acc = sum_d A[o][d]*B[d][p] over padded K=80:
//   d<75 : A = bf16(-2*w), B = bf16_rne(x)
//   d=75 : A = wn_hi, B = 1.0   d=76 : A = wn_lo, B = 1.0
//   d=77 : A = 1.0,   B = pn_hi d=78 : A = 1.0,   B = pn_lo
// acc == d2 = pn + wn - 2*dot; epilogue = v_sqrt(max(acc,0)).
// CORRECTNESS RULE: MFMA operands are wave-collective -- builds may be
// lane-divergent, but every MFMA issues after re-convergence.
// Round-12 theory: writes drain at ~2.9 TB/s (vs 6.6 fill ceiling) because the
// grid-strided strip mapping scatters 128B lines across 64 o-planes with no
// temporal locality. Block = 7 contiguous rows of one image; the 4 waves work
// on 4 consecutive strips at a time -> per-plane write runs become sequential.

#define KH 5
#define KW 5
#define PAD 2
#define CH 3
#define DD 75
#define OC 64
#define HH 224
#define WW 224
#define HW (HH * WW)
#define NSX 7            // 224/32 strips per row
#define RPB 7            // rows per block (224/32 chunks per image)

using short8_t = __attribute__((ext_vector_type(8))) short;
using f32x16   = __attribute__((ext_vector_type(16))) float;

union Oct { unsigned int w[4]; short8_t v; };

__device__ inline unsigned int rne_bf16(float v) {
    return (unsigned int)__builtin_bit_cast(unsigned short, __float2bfloat16(v));
}

__device__ inline float fsqrt_fast(float x) {
    float r;
    asm("v_sqrt_f32 %0, %1" : "=v"(r) : "v"(x));   // ~1ulp; validated round 10
    return r;
}

// window element value; d is constant after unroll+inline -> all math folds.
template<bool EDGE>
__device__ inline float xelem(const float* __restrict__ xb, int y, int xp, int d) {
    if (d >= DD) return 0.f;
    const int c = d / 25, rem = d % 25, i = rem / 5, j = rem % 5;
    int gy = y + i - PAD;
    int gx = xp + j;
    if constexpr (!EDGE) {
        return xb[(c * HH + gy) * WW + gx];
    } else {
        bool ok = ((unsigned)gy < (unsigned)HH) & ((unsigned)gx < (unsigned)WW);
        int gyc = min(max(gy, 0), HH - 1);
        int gxc = min(max(gx, 0), WW - 1);
        float raw = xb[(c * HH + gyc) * WW + gxc];
        return ok ? raw : 0.f;
    }
}

template<int D0, bool EDGE>
__device__ inline void build_oct_rne(const float* __restrict__ xb, int y, int xp,
                                     float& pn, Oct& b) {
#pragma unroll
    for (int rr = 0; rr < 8; rr += 2) {
        float v0 = xelem<EDGE>(xb, y, xp, D0 + rr);
        float v1 = xelem<EDGE>(xb, y, xp, D0 + rr + 1);
        pn = fmaf(v0, v0, pn);
        pn = fmaf(v1, v1, pn);
        b.w[rr >> 1] = rne_bf16(v0) | (rne_bf16(v1) << 16);
    }
}

// A-octet build from LDS-resident w row; also accumulates this lane's
// partial ||w||^2 over the d's it owns (partner half-wave has the rest).
template<int D0>
__device__ inline void build_aoct_wn(const float* wrow, Oct& a, float& wns) {
#pragma unroll
    for (int rr = 0; rr < 8; rr += 2) {
        float r0 = (D0 + rr     < DD) ? wrow[D0 + rr]     : 0.f;
        float r1 = (D0 + rr + 1 < DD) ? wrow[D0 + rr + 1] : 0.f;
        wns = fmaf(r0, r0, wns);
        wns = fmaf(r1, r1, wns);
        a.w[rr >> 1] = rne_bf16(-2.f * r0) | (rne_bf16(-2.f * r1) << 16);
    }
}

#define MFMA(A, B, C) __builtin_amdgcn_mfma_f32_32x32x16_bf16((A), (B), (C), 0, 0, 0)

template<bool EDGE>
__device__ inline void do_strip(const float* __restrict__ xb, int y, int xp, int hi,
                                const Oct (&ah)[2][5], float* __restrict__ op) {
    float pnp = 0.f;
    Oct bh[5];
    // builds divergent on hi (compile-time D0 per half-wave)...
    if (hi == 0) {
        build_oct_rne<0,  EDGE>(xb, y, xp, pnp, bh[0]);
        build_oct_rne<16, EDGE>(xb, y, xp, pnp, bh[1]);
        build_oct_rne<32, EDGE>(xb, y, xp, pnp, bh[2]);
        build_oct_rne<48, EDGE>(xb, y, xp, pnp, bh[3]);
        build_oct_rne<64, EDGE>(xb, y, xp, pnp, bh[4]);
    } else {
        build_oct_rne<8,  EDGE>(xb, y, xp, pnp, bh[0]);
        build_oct_rne<24, EDGE>(xb, y, xp, pnp, bh[1]);
        build_oct_rne<40, EDGE>(xb, y, xp, pnp, bh[2]);
        build_oct_rne<56, EDGE>(xb, y, xp, pnp, bh[3]);
        build_oct_rne<72, EDGE>(xb, y, xp, pnp, bh[4]);   // d75..79 -> 0
    }
    float pn = pnp + __shfl_xor(pnp, 32);   // partner half-wave has other d's
    if (hi == 1) {
        // B pad slots (octet d72..79): elem3=1, elem4=1, elem5=pn_hi, elem6=pn_lo
        unsigned int up  = __builtin_bit_cast(unsigned int, pn);
        float pnhv = __builtin_bit_cast(float, up & 0xFFFF0000u);
        unsigned int pnl = rne_bf16(pn - pnhv);
        bh[4].w[1] |= 0x3F800000u;
        bh[4].w[2]  = 0x3F80u | (up & 0xFFFF0000u);
        bh[4].w[3]  = pnl;
    }

    // ...MFMAs only here, fully re-converged.
    f32x16 acc0 = {0.f,0.f,0.f,0.f,0.f,0.f,0.f,0.f,0.f,0.f,0.f,0.f,0.f,0.f,0.f,0.f};
    f32x16 acc1 = acc0;
#pragma unroll
    for (int st = 0; st < 5; ++st) {
        acc0 = MFMA(ah[0][st].v, bh[st].v, acc0);
        acc1 = MFMA(ah[1][st].v, bh[st].v, acc1);
    }

    // C/D: col = lane&31, row = (reg&3)+8*(reg>>2)+4*hi (+32 for acc1); +4*hi in op.
#pragma unroll
    for (int reg = 0; reg < 16; ++reg) {
        int ob = (reg & 3) + 8 * (reg >> 2);
        op[(size_t)ob * HW]        = fsqrt_fast(fmaxf(acc0[reg], 0.f));
        op[(size_t)(ob + 32) * HW] = fsqrt_fast(fmaxf(acc1[reg], 0.f));
    }
}

__global__ __launch_bounds__(256, 4) void rbf_mfma(const float* __restrict__ x,
                                                   const float* __restrict__ w,
                                                   float* __restrict__ out) {
    __shared__ float wlds[OC * DD];          // 19.2 KB
    const int tid  = threadIdx.x;

    // ---- coalesced global->LDS staging of w (once per block) ----
    for (int idx = tid; idx < OC * DD; idx += 256)
        wlds[idx] = w[idx];
    __syncthreads();

    const int lane = tid & 63;
    const int l31  = lane & 31;
    const int hi   = lane >> 5;

    // ---- A-fragment + wn build from LDS ----
    float wnp[2] = {0.f, 0.f};
    Oct ah[2][5];
    if (hi == 0) {
#pragma unroll
        for (int mt = 0; mt < 2; ++mt) {
            const float* wrow = wlds + (l31 + 32 * mt) * DD;
            build_aoct_wn<0 >(wrow, ah[mt][0], wnp[mt]);
            build_aoct_wn<16>(wrow, ah[mt][1], wnp[mt]);
            build_aoct_wn<32>(wrow, ah[mt][2], wnp[mt]);
            build_aoct_wn<48>(wrow, ah[mt][3], wnp[mt]);
            build_aoct_wn<64>(wrow, ah[mt][4], wnp[mt]);
        }
    } else {
#pragma unroll
        for (int mt = 0; mt < 2; ++mt) {
            const float* wrow = wlds + (l31 + 32 * mt) * DD;
            build_aoct_wn<8 >(wrow, ah[mt][0], wnp[mt]);
            build_aoct_wn<24>(wrow, ah[mt][1], wnp[mt]);
            build_aoct_wn<40>(wrow, ah[mt][2], wnp[mt]);
            build_aoct_wn<56>(wrow, ah[mt][3], wnp[mt]);
            build_aoct_wn<72>(wrow, ah[mt][4], wnp[mt]);
        }
    }
    // full ||w||^2 per mt: partner half-wave (same row) holds the other d's
    float wn0 = wnp[0] + __shfl_xor(wnp[0], 32);
    float wn1 = wnp[1] + __shfl_xor(wnp[1], 32);
    if (hi == 1) {
#pragma unroll
        for (int mt = 0; mt < 2; ++mt) {
            // A pad slots: elem3=wn_hi, elem4=wn_lo, elem5=1.0, elem6=1.0, elem7=0
            float wnv = mt ? wn1 : wn0;
            unsigned int uwn = __builtin_bit_cast(unsigned int, wnv);
            float wnhv = __builtin_bit_cast(float, uwn & 0xFFFF0000u);
            unsigned int wnl = rne_bf16(wnv - wnhv);
            ah[mt][4].w[1] = (ah[mt][4].w[1] & 0xFFFFu) | (uwn & 0xFFFF0000u);
            ah[mt][4].w[2] = wnl | (0x3F80u << 16);
            ah[mt][4].w[3] = 0x3F80u;
        }
    }

    // ---- strip loop: block owns RPB contiguous rows of one image; at any
    // instant the 4 waves process 4 CONSECUTIVE strips (write locality) ----
    const int b  = blockIdx.x >> 5;          // image  (32 chunks per image)
    const int y0 = (blockIdx.x & 31) * RPB;  // first row of this block's chunk
    const int wv = tid >> 6;
    const float* xb = x + (size_t)b * (CH * HW);
    float* outb = out + (size_t)b * OC * HW + (size_t)hi * 4 * HW + l31;

    const int niter = (wv == 0) ? 13 : 12;   // 49 strips = 13+12+12+12
#pragma unroll 1
    for (int it = 0; it < niter; ++it) {
        int sidx = it * 4 + wv;              // 0..48, consecutive across waves
        int r    = (sidx * 37) >> 8;         // sidx / 7  (exact for 0..48)
        int sx   = sidx - r * 7;
        int y    = y0 + r;
        int x0   = sx * 32;
        int xp   = x0 + l31 - PAD;
        float* op = outb + (size_t)y * WW + x0;
        bool interior = (y >= PAD) & (y < HH - PAD) & (sx >= 1) & (sx <= 5);
        if (interior) do_strip<false>(xb, y, xp, hi, ah, op);
        else          do_strip<true >(xb, y, xp, hi, ah, op);
    }
}

extern "C" void kernel_launch(void* const* d_in, const int* in_sizes, int n_in,
                              void* d_out, int out_size, void* d_ws, size_t ws_size,
                              hipStream_t stream) {
    const float* x = (const float*)d_in[0];
    const float* w = (const float*)d_in[1];
    float* out     = (float*)d_out;

    int B       = in_sizes[0] / (CH * HW);   // 32
    int nblocks = B * 32;                    // 32 row-chunks per image, RPB=7

    rbf_mfma<<<nblocks, 256, 0, stream>>>(x, w, out);
}